// Round 10
// baseline (279.156 us; speedup 1.0000x reference)
//
#include <hip/hip_runtime.h>
#include <math.h>

// ---------------------------------------------------------------------------
// 2-layer graph conv (1-wide features), atomic-free via dst-binned counting
// sort (once, reused by both layers) + per-bin LDS accumulation.
//   layer: agg[v] = sum_{(u->v)} x[u];  x = relu(agg * w[i])
//   out   = sigmoid(x + bias)
// Packing: N <= 2^20, BINSZ=2048 -> meta = (dst_low11 << 20) | src20
// R10: R8 base + single-pass rank-in-register scatter WITHOUT the VGPR cap
//      that spilled R9/R5 (launch_bounds(512,2) -> arrays stay in VGPRs),
//      and R8's wave-per-bin coalesced copy-out (R9's binary search dropped).
// ---------------------------------------------------------------------------

#define BINSHIFT 11
#define BINSZ    2048
#define MAXNB    512
#define SCHUNK   16384
#define STHREADS 512
#define RTH      1024

typedef unsigned u32x4 __attribute__((ext_vector_type(4)));

__device__ inline unsigned short f2bf(float f) {
    unsigned u = __float_as_uint(f);
    unsigned r = u + 0x7FFFu + ((u >> 16) & 1u);   // round-to-nearest-even
    return (unsigned short)(r >> 16);
}
__device__ inline float bf2f(unsigned short h) {
    return __uint_as_float(((unsigned)h) << 16);
}

// P0: convert fp32 x -> bf16 table
__global__ void x2bf_kernel(const float* __restrict__ x,
                            unsigned short* __restrict__ xb, int n) {
    int i = blockIdx.x * blockDim.x + threadIdx.x;
    int stride = gridDim.x * blockDim.x;
    for (; i < n; i += stride) xb[i] = f2bf(x[i]);
}

// P1: cursors[b] = b*CAP
__global__ void init_cursors(int* __restrict__ cursors, int NB, int CAP) {
    int t = blockIdx.x * blockDim.x + threadIdx.x;
    if (t < NB) cursors[t] = t * CAP;
}

// A: LDS-staged scatter, single-pass rank-in-register + wave-per-bin copy-out.
// launch_bounds(512,2): <=256 VGPR so meta[32]+rp[32] stay in registers
// (R9's (512,4) cap forced a 64-VGPR tier and spilled -> +14us).
__global__ __launch_bounds__(STHREADS, 2)
void scatter_staged(const int* __restrict__ src, const int* __restrict__ dst,
                    int nE, int NB, int CAP, int* __restrict__ cursors,
                    unsigned int* __restrict__ binned) {
    __shared__ unsigned int stage[SCHUNK];   // 64 KB
    __shared__ int cnt[MAXNB];
    __shared__ int lstart[MAXNB];
    __shared__ int lscan[MAXNB];
    __shared__ int delta[MAXNB];

    int t = threadIdx.x;
    int cb = blockIdx.x * SCHUNK;
    int nHere = nE - cb;
    if (nHere > SCHUNK) nHere = SCHUNK;
    bool full = (nHere == SCHUNK);

    cnt[t] = 0;
    __syncthreads();

    // ---- pass 1: load once; count + rank; meta & (bin|rank) into VGPRs ----
    unsigned meta[32], rp[32];
    if (full) {
        const int4* d4 = reinterpret_cast<const int4*>(dst + cb);
        const int4* s4 = reinterpret_cast<const int4*>(src + cb);
        #pragma unroll
        for (int k = 0; k < 8; ++k) {
            int4 d = d4[k * STHREADS + t];
            int4 s = s4[k * STHREADS + t];
            int b, r;
            b = d.x >> BINSHIFT; r = atomicAdd(&cnt[b], 1);
            meta[k * 4 + 0] = ((unsigned)(d.x & (BINSZ - 1)) << 20) | (unsigned)s.x;
            rp[k * 4 + 0]   = ((unsigned)b << 14) | (unsigned)r;     // r < 16384
            b = d.y >> BINSHIFT; r = atomicAdd(&cnt[b], 1);
            meta[k * 4 + 1] = ((unsigned)(d.y & (BINSZ - 1)) << 20) | (unsigned)s.y;
            rp[k * 4 + 1]   = ((unsigned)b << 14) | (unsigned)r;
            b = d.z >> BINSHIFT; r = atomicAdd(&cnt[b], 1);
            meta[k * 4 + 2] = ((unsigned)(d.z & (BINSZ - 1)) << 20) | (unsigned)s.z;
            rp[k * 4 + 2]   = ((unsigned)b << 14) | (unsigned)r;
            b = d.w >> BINSHIFT; r = atomicAdd(&cnt[b], 1);
            meta[k * 4 + 3] = ((unsigned)(d.w & (BINSZ - 1)) << 20) | (unsigned)s.w;
            rp[k * 4 + 3]   = ((unsigned)b << 14) | (unsigned)r;
        }
    } else {
        for (int j = t; j < nHere; j += STHREADS)
            atomicAdd(&cnt[dst[cb + j] >> BINSHIFT], 1);
    }
    __syncthreads();

    // ---- scan (Hillis-Steele over 512) ----
    int c = cnt[t];
    lscan[t] = c;
    __syncthreads();
    for (int off = 1; off < MAXNB; off <<= 1) {
        int v = (t >= off) ? lscan[t - off] : 0;
        __syncthreads();
        lscan[t] += v;
        __syncthreads();
    }
    lstart[t] = lscan[t] - c;

    // reserve global space (one atomic per non-empty bin)
    int gb = 0;
    if (t < NB && c) gb = atomicAdd(&cursors[t], c);
    delta[t] = gb - lstart[t];
    cnt[t] = 0;                 // partial path re-uses cnt for ranking
    __syncthreads();

    // ---- pass 2: place meta into stage (bin-ordered), pure reg->LDS ----
    if (full) {
        #pragma unroll
        for (int k = 0; k < 32; ++k) {
            unsigned q = rp[k];
            stage[lstart[q >> 14] + (q & 0x3FFFu)] = meta[k];
        }
    } else {
        for (int j = t; j < nHere; j += STHREADS) {
            int dv = dst[cb + j];
            int sv = src[cb + j];
            int b = dv >> BINSHIFT;
            int r = atomicAdd(&cnt[b], 1);
            stage[lstart[b] + r] = ((unsigned)(dv & (BINSZ - 1)) << 20) | (unsigned)sv;
        }
        __syncthreads();
        // restore cnt[t] = segment length for copy-out
        cnt[t] = lscan[t] - lstart[t];
    }
    __syncthreads();

    // ---- copy-out: one wave per bin, coalesced segment copy ----
    int wave = t >> 6, lane = t & 63;
    for (int b = wave; b < NB; b += STHREADS / 64) {
        int s0 = lstart[b];
        int s1 = lscan[b];              // inclusive scan = segment end
        int dlt = delta[b];
        int gmax = (b + 1) * CAP;
        for (int j = s0 + lane; j < s1; j += 64) {
            int gi = dlt + j;
            if (gi < gmax) binned[gi] = stage[j];   // capacity clamp
        }
    }
}

// B: per-bin reduce with bf16 gather table (R8, unchanged).
template <int FINAL>
__global__ __launch_bounds__(RTH, 8)
void reduce_bf(const unsigned int* __restrict__ binned,
               const int* __restrict__ cursors, int CAP,
               const unsigned short* __restrict__ gin,
               const float* __restrict__ wp,
               const float* __restrict__ bp,
               unsigned short* __restrict__ hout,
               float* __restrict__ fout, int n) {
    __shared__ float acc[BINSZ];
    int b = blockIdx.x;
    int t = threadIdx.x;
    acc[t] = 0.f;
    acc[t + RTH] = 0.f;
    __syncthreads();

    int s = b * CAP;            // CAP % 4 == 0 -> 16B-aligned start
    int e = cursors[b];
    int a1 = e & ~3;

    const u32x4* b4 = reinterpret_cast<const u32x4*>(binned);
    int q1 = a1 >> 2;
    for (int q = (s >> 2) + t; q < q1; q += RTH) {
        u32x4 p = b4[q];
        float v0 = bf2f(gin[p.x & 0xFFFFFu]);
        float v1 = bf2f(gin[p.y & 0xFFFFFu]);
        float v2 = bf2f(gin[p.z & 0xFFFFFu]);
        float v3 = bf2f(gin[p.w & 0xFFFFFu]);
        atomicAdd(&acc[p.x >> 20], v0);
        atomicAdd(&acc[p.y >> 20], v1);
        atomicAdd(&acc[p.z >> 20], v2);
        atomicAdd(&acc[p.w >> 20], v3);
    }
    if (a1 + t < e) {
        unsigned p = binned[a1 + t];
        atomicAdd(&acc[p >> 20], bf2f(gin[p & 0xFFFFFu]));
    }
    __syncthreads();

    float w = wp[0];
    float bias = FINAL ? bp[0] : 0.f;
    int nodeBase = b << BINSHIFT;
    #pragma unroll
    for (int k = 0; k < BINSZ / RTH; ++k) {
        int node = nodeBase + t + k * RTH;
        if (node < n) {
            float h = fmaxf(acc[t + k * RTH] * w, 0.f);
            if (FINAL) fout[node] = 1.f / (1.f + __expf(-(h + bias)));
            else       hout[node] = f2bf(h);
        }
    }
}

// ========================= fallback (round-1) path =========================

__global__ void scatter_add4(const float* __restrict__ x,
                             const int* __restrict__ src,
                             const int* __restrict__ dst,
                             float* __restrict__ agg,
                             int nE4, int nE) {
    int tid = blockIdx.x * blockDim.x + threadIdx.x;
    int stride = gridDim.x * blockDim.x;
    for (int i = tid; i < nE4; i += stride) {
        int4 s = reinterpret_cast<const int4*>(src)[i];
        int4 d = reinterpret_cast<const int4*>(dst)[i];
        atomicAdd(&agg[d.x], x[s.x]);
        atomicAdd(&agg[d.y], x[s.y]);
        atomicAdd(&agg[d.z], x[s.z]);
        atomicAdd(&agg[d.w], x[s.w]);
    }
    int e = nE4 * 4 + tid;
    if (e < nE) atomicAdd(&agg[dst[e]], x[src[e]]);
}

__global__ void relu_scale4(float* __restrict__ a, const float* __restrict__ w, int n4) {
    float wv = w[0];
    int tid = blockIdx.x * blockDim.x + threadIdx.x;
    int stride = gridDim.x * blockDim.x;
    for (int i = tid; i < n4; i += stride) {
        float4 v = reinterpret_cast<float4*>(a)[i];
        v.x = fmaxf(v.x * wv, 0.0f);
        v.y = fmaxf(v.y * wv, 0.0f);
        v.z = fmaxf(v.z * wv, 0.0f);
        v.w = fmaxf(v.w * wv, 0.0f);
        reinterpret_cast<float4*>(a)[i] = v;
    }
}

__global__ void finish4(float* __restrict__ o, const float* __restrict__ w,
                        const float* __restrict__ bias, int n4) {
    float wv = w[0];
    float b = bias[0];
    int tid = blockIdx.x * blockDim.x + threadIdx.x;
    int stride = gridDim.x * blockDim.x;
    for (int i = tid; i < n4; i += stride) {
        float4 v = reinterpret_cast<float4*>(o)[i];
        float sx = fmaxf(v.x * wv, 0.0f) + b;
        float sy = fmaxf(v.y * wv, 0.0f) + b;
        float sz = fmaxf(v.z * wv, 0.0f) + b;
        float sw = fmaxf(v.w * wv, 0.0f) + b;
        v.x = 1.0f / (1.0f + __expf(-sx));
        v.y = 1.0f / (1.0f + __expf(-sy));
        v.z = 1.0f / (1.0f + __expf(-sz));
        v.w = 1.0f / (1.0f + __expf(-sw));
        reinterpret_cast<float4*>(o)[i] = v;
    }
}

// ========================= launcher =========================

extern "C" void kernel_launch(void* const* d_in, const int* in_sizes, int n_in,
                              void* d_out, int out_size, void* d_ws, size_t ws_size,
                              hipStream_t stream) {
    const float* x    = (const float*)d_in[0];
    const int*   ei   = (const int*)d_in[1];
    const float* w    = (const float*)d_in[2];
    const float* bias = (const float*)d_in[3];

    int n  = in_sizes[0];
    int nE = in_sizes[1] / 2;
    const int* src = ei;
    const int* dst = ei + nE;
    float* out = (float*)d_out;

    int NB = (n + BINSZ - 1) >> BINSHIFT;

    // capacity per bin: avg + max(avg/8, 4096), multiple of 4 (uint4 starts)
    int avg = (nE + (NB > 0 ? NB : 1) - 1) / (NB > 0 ? NB : 1);
    int slack = avg / 8; if (slack < 4096) slack = 4096;
    int CAP = (avg + slack + 3) & ~3;

    // ws layout: binned[NB*CAP] | cursors[512] | xb[n] bf16 | h1b[n] bf16
    size_t sz_binned = (((size_t)NB * (size_t)CAP) * 4 + 255) & ~(size_t)255;
    size_t sz_cur    = (MAXNB * 4 + 255) & ~(size_t)255;
    size_t sz_tab    = ((size_t)n * 2 + 255) & ~(size_t)255;
    size_t need      = sz_binned + sz_cur + 2 * sz_tab;

    bool can_fast = (n <= (1 << 20)) && (NB <= MAXNB) && (ws_size >= need);

    if (can_fast) {
        unsigned int*   binned  = (unsigned int*)d_ws;
        int*            cursors = (int*)((char*)d_ws + sz_binned);
        unsigned short* xb      = (unsigned short*)((char*)d_ws + sz_binned + sz_cur);
        unsigned short* h1b     = (unsigned short*)((char*)d_ws + sz_binned + sz_cur + sz_tab);

        dim3 blk256(256), blk512(512), blk1024(RTH);
        x2bf_kernel<<<1024, blk256, 0, stream>>>(x, xb, n);
        init_cursors<<<2, blk256, 0, stream>>>(cursors, NB, CAP);

        int nChunks = (nE + SCHUNK - 1) / SCHUNK;
        scatter_staged<<<nChunks, blk512, 0, stream>>>(src, dst, nE, NB, CAP,
                                                       cursors, binned);

        reduce_bf<0><<<NB, blk1024, 0, stream>>>(binned, cursors, CAP, xb,
                                                 w + 0, bias, h1b, nullptr, n);
        reduce_bf<1><<<NB, blk1024, 0, stream>>>(binned, cursors, CAP, h1b,
                                                 w + 1, bias, nullptr, out, n);
    } else {
        float* agg1 = (float*)d_ws;
        hipMemsetAsync(agg1, 0, (size_t)n * sizeof(float), stream);
        hipMemsetAsync(out,  0, (size_t)n * sizeof(float), stream);
        int nE4 = nE / 4;
        dim3 blk(256);
        int eblocks = (nE4 + 255) / 256; if (eblocks > 4096) eblocks = 4096;
        int n4 = n / 4;
        int nblocks = (n4 + 255) / 256; if (nblocks > 2048) nblocks = 2048;
        scatter_add4<<<eblocks, blk, 0, stream>>>(x, src, dst, agg1, nE4, nE);
        relu_scale4<<<nblocks, blk, 0, stream>>>(agg1, w + 0, n4);
        scatter_add4<<<eblocks, blk, 0, stream>>>(agg1, src, dst, out, nE4, nE);
        finish4<<<nblocks, blk, 0, stream>>>(out, w + 1, bias, n4);
    }
}

// Round 11
// 269.575 us; speedup vs baseline: 1.0355x; 1.0355x over previous
//
#include <hip/hip_runtime.h>
#include <math.h>

// ---------------------------------------------------------------------------
// 2-layer graph conv (1-wide features), atomic-free via dst-binned counting
// sort (once, reused by both layers) + per-bin LDS accumulation.
//   layer: agg[v] = sum_{(u->v)} x[u];  x = relu(agg * w[i])
//   out   = sigmoid(x + bias)
// Packing: N <= 2^20, BINSZ=2048 -> meta = (dst_low11 << 20) | src20
// R11: exact R8 revert (best, 257us: 2-pass scatter VGPR52 + bf16 tables +
//      capacity bins) with ONE change: copy-out groups 4 consecutive bins
//      per wave (contiguous in stage) -> lane efficiency 52% -> ~80%.
//      (R9/R10 single-pass rank-in-register falsified 3x: VGPR spill.)
// ---------------------------------------------------------------------------

#define BINSHIFT 11
#define BINSZ    2048
#define MAXNB    512
#define SCHUNK   16384
#define STHREADS 512
#define RTH      1024

typedef unsigned u32x4 __attribute__((ext_vector_type(4)));

__device__ inline unsigned short f2bf(float f) {
    unsigned u = __float_as_uint(f);
    unsigned r = u + 0x7FFFu + ((u >> 16) & 1u);   // round-to-nearest-even
    return (unsigned short)(r >> 16);
}
__device__ inline float bf2f(unsigned short h) {
    return __uint_as_float(((unsigned)h) << 16);
}

// P0: convert fp32 x -> bf16 table
__global__ void x2bf_kernel(const float* __restrict__ x,
                            unsigned short* __restrict__ xb, int n) {
    int i = blockIdx.x * blockDim.x + threadIdx.x;
    int stride = gridDim.x * blockDim.x;
    for (; i < n; i += stride) xb[i] = f2bf(x[i]);
}

// P1: cursors[b] = b*CAP
__global__ void init_cursors(int* __restrict__ cursors, int NB, int CAP) {
    int t = blockIdx.x * blockDim.x + threadIdx.x;
    if (t < NB) cursors[t] = t * CAP;
}

// A: LDS-staged scatter (R8-proven 2-pass hot loops; VGPR 52, no spill).
__global__ __launch_bounds__(STHREADS, 2)
void scatter_staged(const int* __restrict__ src, const int* __restrict__ dst,
                    int nE, int NB, int CAP, int* __restrict__ cursors,
                    unsigned int* __restrict__ binned) {
    __shared__ unsigned int stage[SCHUNK];
    __shared__ int cnt[MAXNB];
    __shared__ int lstart[MAXNB];
    __shared__ int lscan[MAXNB];
    __shared__ int delta[MAXNB];

    int t = threadIdx.x;
    int cb = blockIdx.x * SCHUNK;
    int nHere = nE - cb;
    if (nHere > SCHUNK) nHere = SCHUNK;

    cnt[t] = 0;
    __syncthreads();

    // ---- pass 1: count this chunk's bins ----
    if (nHere == SCHUNK) {
        const int4* d4 = reinterpret_cast<const int4*>(dst + cb);
        #pragma unroll
        for (int k = 0; k < SCHUNK / 4 / STHREADS; ++k) {
            int4 d = d4[k * STHREADS + t];
            atomicAdd(&cnt[d.x >> BINSHIFT], 1);
            atomicAdd(&cnt[d.y >> BINSHIFT], 1);
            atomicAdd(&cnt[d.z >> BINSHIFT], 1);
            atomicAdd(&cnt[d.w >> BINSHIFT], 1);
        }
    } else {
        for (int j = t; j < nHere; j += STHREADS)
            atomicAdd(&cnt[dst[cb + j] >> BINSHIFT], 1);
    }
    __syncthreads();

    // ---- scan (Hillis-Steele over 512) ----
    int c = cnt[t];
    lscan[t] = c;
    __syncthreads();
    for (int off = 1; off < MAXNB; off <<= 1) {
        int v = (t >= off) ? lscan[t - off] : 0;
        __syncthreads();
        lscan[t] += v;
        __syncthreads();
    }
    lstart[t] = lscan[t] - c;

    // reserve global space (one atomic per non-empty bin)
    int gb = 0;
    if (t < NB && c) gb = atomicAdd(&cursors[t], c);
    delta[t] = gb - lstart[t];
    cnt[t] = 0;
    __syncthreads();

    // ---- pass 2: rank + stage (bin-ordered); dst/src re-read is L2-hot ----
    if (nHere == SCHUNK) {
        const int4* d4 = reinterpret_cast<const int4*>(dst + cb);
        const int4* s4 = reinterpret_cast<const int4*>(src + cb);
        #pragma unroll
        for (int k = 0; k < SCHUNK / 4 / STHREADS; ++k) {
            int4 d = d4[k * STHREADS + t];
            int4 s = s4[k * STHREADS + t];
            int b, r;
            b = d.x >> BINSHIFT; r = atomicAdd(&cnt[b], 1);
            stage[lstart[b] + r] = ((unsigned)(d.x & (BINSZ - 1)) << 20) | (unsigned)s.x;
            b = d.y >> BINSHIFT; r = atomicAdd(&cnt[b], 1);
            stage[lstart[b] + r] = ((unsigned)(d.y & (BINSZ - 1)) << 20) | (unsigned)s.y;
            b = d.z >> BINSHIFT; r = atomicAdd(&cnt[b], 1);
            stage[lstart[b] + r] = ((unsigned)(d.z & (BINSZ - 1)) << 20) | (unsigned)s.z;
            b = d.w >> BINSHIFT; r = atomicAdd(&cnt[b], 1);
            stage[lstart[b] + r] = ((unsigned)(d.w & (BINSZ - 1)) << 20) | (unsigned)s.w;
        }
    } else {
        for (int j = t; j < nHere; j += STHREADS) {
            int dv = dst[cb + j];
            int sv = src[cb + j];
            int b = dv >> BINSHIFT;
            int r = atomicAdd(&cnt[b], 1);
            stage[lstart[b] + r] = ((unsigned)(dv & (BINSZ - 1)) << 20) | (unsigned)sv;
        }
    }
    __syncthreads();

    // ---- copy-out (R11): one wave per GROUP of 4 consecutive bins.
    // Segments are contiguous in stage, so the group is one contiguous
    // range; each lane picks its bin via <=3 compares on lscan.
    int wave = t >> 6, lane = t & 63;
    int nGroups = (NB + 3) >> 2;
    for (int g = wave; g < nGroups; g += STHREADS / 64) {
        int b0 = g << 2;
        int bend = b0 + 4; if (bend > NB) bend = NB;
        int s0 = lstart[b0];
        int s1 = lscan[bend - 1];
        for (int j = s0 + lane; j < s1; j += 64) {
            int b = b0;
            while (b + 1 < bend && j >= lscan[b]) ++b;
            int gi = delta[b] + j;
            if (gi < (b + 1) * CAP) binned[gi] = stage[j];   // capacity clamp
        }
    }
}

// B: per-bin reduce with bf16 gather table (R8, unchanged).
template <int FINAL>
__global__ __launch_bounds__(RTH, 8)
void reduce_bf(const unsigned int* __restrict__ binned,
               const int* __restrict__ cursors, int CAP,
               const unsigned short* __restrict__ gin,
               const float* __restrict__ wp,
               const float* __restrict__ bp,
               unsigned short* __restrict__ hout,
               float* __restrict__ fout, int n) {
    __shared__ float acc[BINSZ];
    int b = blockIdx.x;
    int t = threadIdx.x;
    acc[t] = 0.f;
    acc[t + RTH] = 0.f;
    __syncthreads();

    int s = b * CAP;            // CAP % 4 == 0 -> 16B-aligned start
    int e = cursors[b];
    int a1 = e & ~3;

    const u32x4* b4 = reinterpret_cast<const u32x4*>(binned);
    int q1 = a1 >> 2;
    for (int q = (s >> 2) + t; q < q1; q += RTH) {
        u32x4 p = b4[q];
        float v0 = bf2f(gin[p.x & 0xFFFFFu]);
        float v1 = bf2f(gin[p.y & 0xFFFFFu]);
        float v2 = bf2f(gin[p.z & 0xFFFFFu]);
        float v3 = bf2f(gin[p.w & 0xFFFFFu]);
        atomicAdd(&acc[p.x >> 20], v0);
        atomicAdd(&acc[p.y >> 20], v1);
        atomicAdd(&acc[p.z >> 20], v2);
        atomicAdd(&acc[p.w >> 20], v3);
    }
    if (a1 + t < e) {
        unsigned p = binned[a1 + t];
        atomicAdd(&acc[p >> 20], bf2f(gin[p & 0xFFFFFu]));
    }
    __syncthreads();

    float w = wp[0];
    float bias = FINAL ? bp[0] : 0.f;
    int nodeBase = b << BINSHIFT;
    #pragma unroll
    for (int k = 0; k < BINSZ / RTH; ++k) {
        int node = nodeBase + t + k * RTH;
        if (node < n) {
            float h = fmaxf(acc[t + k * RTH] * w, 0.f);
            if (FINAL) fout[node] = 1.f / (1.f + __expf(-(h + bias)));
            else       hout[node] = f2bf(h);
        }
    }
}

// ========================= fallback (round-1) path =========================

__global__ void scatter_add4(const float* __restrict__ x,
                             const int* __restrict__ src,
                             const int* __restrict__ dst,
                             float* __restrict__ agg,
                             int nE4, int nE) {
    int tid = blockIdx.x * blockDim.x + threadIdx.x;
    int stride = gridDim.x * blockDim.x;
    for (int i = tid; i < nE4; i += stride) {
        int4 s = reinterpret_cast<const int4*>(src)[i];
        int4 d = reinterpret_cast<const int4*>(dst)[i];
        atomicAdd(&agg[d.x], x[s.x]);
        atomicAdd(&agg[d.y], x[s.y]);
        atomicAdd(&agg[d.z], x[s.z]);
        atomicAdd(&agg[d.w], x[s.w]);
    }
    int e = nE4 * 4 + tid;
    if (e < nE) atomicAdd(&agg[dst[e]], x[src[e]]);
}

__global__ void relu_scale4(float* __restrict__ a, const float* __restrict__ w, int n4) {
    float wv = w[0];
    int tid = blockIdx.x * blockDim.x + threadIdx.x;
    int stride = gridDim.x * blockDim.x;
    for (int i = tid; i < n4; i += stride) {
        float4 v = reinterpret_cast<float4*>(a)[i];
        v.x = fmaxf(v.x * wv, 0.0f);
        v.y = fmaxf(v.y * wv, 0.0f);
        v.z = fmaxf(v.z * wv, 0.0f);
        v.w = fmaxf(v.w * wv, 0.0f);
        reinterpret_cast<float4*>(a)[i] = v;
    }
}

__global__ void finish4(float* __restrict__ o, const float* __restrict__ w,
                        const float* __restrict__ bias, int n4) {
    float wv = w[0];
    float b = bias[0];
    int tid = blockIdx.x * blockDim.x + threadIdx.x;
    int stride = gridDim.x * blockDim.x;
    for (int i = tid; i < n4; i += stride) {
        float4 v = reinterpret_cast<float4*>(o)[i];
        float sx = fmaxf(v.x * wv, 0.0f) + b;
        float sy = fmaxf(v.y * wv, 0.0f) + b;
        float sz = fmaxf(v.z * wv, 0.0f) + b;
        float sw = fmaxf(v.w * wv, 0.0f) + b;
        v.x = 1.0f / (1.0f + __expf(-sx));
        v.y = 1.0f / (1.0f + __expf(-sy));
        v.z = 1.0f / (1.0f + __expf(-sz));
        v.w = 1.0f / (1.0f + __expf(-sw));
        reinterpret_cast<float4*>(o)[i] = v;
    }
}

// ========================= launcher =========================

extern "C" void kernel_launch(void* const* d_in, const int* in_sizes, int n_in,
                              void* d_out, int out_size, void* d_ws, size_t ws_size,
                              hipStream_t stream) {
    const float* x    = (const float*)d_in[0];
    const int*   ei   = (const int*)d_in[1];
    const float* w    = (const float*)d_in[2];
    const float* bias = (const float*)d_in[3];

    int n  = in_sizes[0];
    int nE = in_sizes[1] / 2;
    const int* src = ei;
    const int* dst = ei + nE;
    float* out = (float*)d_out;

    int NB = (n + BINSZ - 1) >> BINSHIFT;

    // capacity per bin: avg + max(avg/8, 4096), multiple of 4 (uint4 starts)
    int avg = (nE + (NB > 0 ? NB : 1) - 1) / (NB > 0 ? NB : 1);
    int slack = avg / 8; if (slack < 4096) slack = 4096;
    int CAP = (avg + slack + 3) & ~3;

    // ws layout: binned[NB*CAP] | cursors[512] | xb[n] bf16 | h1b[n] bf16
    size_t sz_binned = (((size_t)NB * (size_t)CAP) * 4 + 255) & ~(size_t)255;
    size_t sz_cur    = (MAXNB * 4 + 255) & ~(size_t)255;
    size_t sz_tab    = ((size_t)n * 2 + 255) & ~(size_t)255;
    size_t need      = sz_binned + sz_cur + 2 * sz_tab;

    bool can_fast = (n <= (1 << 20)) && (NB <= MAXNB) && (ws_size >= need);

    if (can_fast) {
        unsigned int*   binned  = (unsigned int*)d_ws;
        int*            cursors = (int*)((char*)d_ws + sz_binned);
        unsigned short* xb      = (unsigned short*)((char*)d_ws + sz_binned + sz_cur);
        unsigned short* h1b     = (unsigned short*)((char*)d_ws + sz_binned + sz_cur + sz_tab);

        dim3 blk256(256), blk512(512), blk1024(RTH);
        x2bf_kernel<<<1024, blk256, 0, stream>>>(x, xb, n);
        init_cursors<<<2, blk256, 0, stream>>>(cursors, NB, CAP);

        int nChunks = (nE + SCHUNK - 1) / SCHUNK;
        scatter_staged<<<nChunks, blk512, 0, stream>>>(src, dst, nE, NB, CAP,
                                                       cursors, binned);

        reduce_bf<0><<<NB, blk1024, 0, stream>>>(binned, cursors, CAP, xb,
                                                 w + 0, bias, h1b, nullptr, n);
        reduce_bf<1><<<NB, blk1024, 0, stream>>>(binned, cursors, CAP, h1b,
                                                 w + 1, bias, nullptr, out, n);
    } else {
        float* agg1 = (float*)d_ws;
        hipMemsetAsync(agg1, 0, (size_t)n * sizeof(float), stream);
        hipMemsetAsync(out,  0, (size_t)n * sizeof(float), stream);
        int nE4 = nE / 4;
        dim3 blk(256);
        int eblocks = (nE4 + 255) / 256; if (eblocks > 4096) eblocks = 4096;
        int n4 = n / 4;
        int nblocks = (n4 + 255) / 256; if (nblocks > 2048) nblocks = 2048;
        scatter_add4<<<eblocks, blk, 0, stream>>>(x, src, dst, agg1, nE4, nE);
        relu_scale4<<<nblocks, blk, 0, stream>>>(agg1, w + 0, n4);
        scatter_add4<<<eblocks, blk, 0, stream>>>(agg1, src, dst, out, nE4, nE);
        finish4<<<nblocks, blk, 0, stream>>>(out, w + 1, bias, n4);
    }
}

// Round 12
// 256.919 us; speedup vs baseline: 1.0866x; 1.0493x over previous
//
#include <hip/hip_runtime.h>
#include <math.h>

// ---------------------------------------------------------------------------
// 2-layer graph conv (1-wide features), atomic-free via dst-binned counting
// sort (once, reused by both layers) + per-bin LDS accumulation.
//   layer: agg[v] = sum_{(u->v)} x[u];  x = relu(agg * w[i])
//   out   = sigmoid(x + bias)
// Packing: N <= 2^20, BINSZ=2048 -> meta = (dst_low11 << 20) | src20
// R12: exact R8 (best, 257us) + (1) reduce gather ILP 4->8 (two uint4 per
//      iter, 8 gathers in flight before atomics — tests the latency/MSHR
//      theory cleanly, no nt-load confound), (2) x2bf+init_cursors merged.
// ---------------------------------------------------------------------------

#define BINSHIFT 11
#define BINSZ    2048
#define MAXNB    512
#define SCHUNK   16384
#define STHREADS 512
#define RTH      1024

typedef unsigned u32x4 __attribute__((ext_vector_type(4)));

__device__ inline unsigned short f2bf(float f) {
    unsigned u = __float_as_uint(f);
    unsigned r = u + 0x7FFFu + ((u >> 16) & 1u);   // round-to-nearest-even
    return (unsigned short)(r >> 16);
}
__device__ inline float bf2f(unsigned short h) {
    return __uint_as_float(((unsigned)h) << 16);
}

// P: fused prep — convert fp32 x -> bf16 table, init cursors[b] = b*CAP
__global__ void prep_kernel(const float* __restrict__ x,
                            unsigned short* __restrict__ xb, int n,
                            int* __restrict__ cursors, int NB, int CAP) {
    int tid = blockIdx.x * blockDim.x + threadIdx.x;
    if (tid < NB) cursors[tid] = tid * CAP;
    int stride = gridDim.x * blockDim.x;
    for (int i = tid; i < n; i += stride) xb[i] = f2bf(x[i]);
}

// A: LDS-staged scatter (R8-proven, byte-identical hot loops; VGPR 52).
__global__ __launch_bounds__(STHREADS, 2)
void scatter_staged(const int* __restrict__ src, const int* __restrict__ dst,
                    int nE, int NB, int CAP, int* __restrict__ cursors,
                    unsigned int* __restrict__ binned) {
    __shared__ unsigned int stage[SCHUNK];
    __shared__ int cnt[MAXNB];
    __shared__ int lstart[MAXNB];
    __shared__ int lscan[MAXNB];
    __shared__ int delta[MAXNB];

    int t = threadIdx.x;
    int cb = blockIdx.x * SCHUNK;
    int nHere = nE - cb;
    if (nHere > SCHUNK) nHere = SCHUNK;

    cnt[t] = 0;
    __syncthreads();

    // ---- pass 1: count this chunk's bins ----
    if (nHere == SCHUNK) {
        const int4* d4 = reinterpret_cast<const int4*>(dst + cb);
        #pragma unroll
        for (int k = 0; k < SCHUNK / 4 / STHREADS; ++k) {
            int4 d = d4[k * STHREADS + t];
            atomicAdd(&cnt[d.x >> BINSHIFT], 1);
            atomicAdd(&cnt[d.y >> BINSHIFT], 1);
            atomicAdd(&cnt[d.z >> BINSHIFT], 1);
            atomicAdd(&cnt[d.w >> BINSHIFT], 1);
        }
    } else {
        for (int j = t; j < nHere; j += STHREADS)
            atomicAdd(&cnt[dst[cb + j] >> BINSHIFT], 1);
    }
    __syncthreads();

    // ---- scan (Hillis-Steele over 512) ----
    int c = cnt[t];
    lscan[t] = c;
    __syncthreads();
    for (int off = 1; off < MAXNB; off <<= 1) {
        int v = (t >= off) ? lscan[t - off] : 0;
        __syncthreads();
        lscan[t] += v;
        __syncthreads();
    }
    lstart[t] = lscan[t] - c;

    // reserve global space (one atomic per non-empty bin)
    int gb = 0;
    if (t < NB && c) gb = atomicAdd(&cursors[t], c);
    delta[t] = gb - lstart[t];
    cnt[t] = 0;
    __syncthreads();

    // ---- pass 2: rank + stage (bin-ordered); dst/src re-read is L2-hot ----
    if (nHere == SCHUNK) {
        const int4* d4 = reinterpret_cast<const int4*>(dst + cb);
        const int4* s4 = reinterpret_cast<const int4*>(src + cb);
        #pragma unroll
        for (int k = 0; k < SCHUNK / 4 / STHREADS; ++k) {
            int4 d = d4[k * STHREADS + t];
            int4 s = s4[k * STHREADS + t];
            int b, r;
            b = d.x >> BINSHIFT; r = atomicAdd(&cnt[b], 1);
            stage[lstart[b] + r] = ((unsigned)(d.x & (BINSZ - 1)) << 20) | (unsigned)s.x;
            b = d.y >> BINSHIFT; r = atomicAdd(&cnt[b], 1);
            stage[lstart[b] + r] = ((unsigned)(d.y & (BINSZ - 1)) << 20) | (unsigned)s.y;
            b = d.z >> BINSHIFT; r = atomicAdd(&cnt[b], 1);
            stage[lstart[b] + r] = ((unsigned)(d.z & (BINSZ - 1)) << 20) | (unsigned)s.z;
            b = d.w >> BINSHIFT; r = atomicAdd(&cnt[b], 1);
            stage[lstart[b] + r] = ((unsigned)(d.w & (BINSZ - 1)) << 20) | (unsigned)s.w;
        }
    } else {
        for (int j = t; j < nHere; j += STHREADS) {
            int dv = dst[cb + j];
            int sv = src[cb + j];
            int b = dv >> BINSHIFT;
            int r = atomicAdd(&cnt[b], 1);
            stage[lstart[b] + r] = ((unsigned)(dv & (BINSZ - 1)) << 20) | (unsigned)sv;
        }
    }
    __syncthreads();

    // ---- copy-out: one wave per bin, coalesced segment copy (R8) ----
    int wave = t >> 6, lane = t & 63;
    for (int b = wave; b < NB; b += STHREADS / 64) {
        int s0 = lstart[b];
        int s1 = lscan[b];
        int dlt = delta[b];
        int gmax = (b + 1) * CAP;
        for (int j = s0 + lane; j < s1; j += 64) {
            int gi = dlt + j;
            if (gi < gmax) binned[gi] = stage[j];   // capacity clamp
        }
    }
}

// B: per-bin reduce, bf16 gather table, 8-deep gather ILP (R12).
template <int FINAL>
__global__ __launch_bounds__(RTH, 8)
void reduce_bf(const unsigned int* __restrict__ binned,
               const int* __restrict__ cursors, int CAP,
               const unsigned short* __restrict__ gin,
               const float* __restrict__ wp,
               const float* __restrict__ bp,
               unsigned short* __restrict__ hout,
               float* __restrict__ fout, int n) {
    __shared__ float acc[BINSZ];
    int b = blockIdx.x;
    int t = threadIdx.x;
    acc[t] = 0.f;
    acc[t + RTH] = 0.f;
    __syncthreads();

    int s = b * CAP;            // CAP % 4 == 0 -> 16B-aligned start
    int e = cursors[b];
    int a1 = e & ~3;

    const u32x4* b4 = reinterpret_cast<const u32x4*>(binned);
    int q1 = a1 >> 2;
    int q = (s >> 2) + t;
    // 8 gathers in flight per thread before any LDS atomic
    for (; q + RTH < q1; q += 2 * RTH) {
        u32x4 pA = b4[q];
        u32x4 pB = b4[q + RTH];
        float v0 = bf2f(gin[pA.x & 0xFFFFFu]);
        float v1 = bf2f(gin[pA.y & 0xFFFFFu]);
        float v2 = bf2f(gin[pA.z & 0xFFFFFu]);
        float v3 = bf2f(gin[pA.w & 0xFFFFFu]);
        float v4 = bf2f(gin[pB.x & 0xFFFFFu]);
        float v5 = bf2f(gin[pB.y & 0xFFFFFu]);
        float v6 = bf2f(gin[pB.z & 0xFFFFFu]);
        float v7 = bf2f(gin[pB.w & 0xFFFFFu]);
        atomicAdd(&acc[pA.x >> 20], v0);
        atomicAdd(&acc[pA.y >> 20], v1);
        atomicAdd(&acc[pA.z >> 20], v2);
        atomicAdd(&acc[pA.w >> 20], v3);
        atomicAdd(&acc[pB.x >> 20], v4);
        atomicAdd(&acc[pB.y >> 20], v5);
        atomicAdd(&acc[pB.z >> 20], v6);
        atomicAdd(&acc[pB.w >> 20], v7);
    }
    for (; q < q1; q += RTH) {
        u32x4 p = b4[q];
        float v0 = bf2f(gin[p.x & 0xFFFFFu]);
        float v1 = bf2f(gin[p.y & 0xFFFFFu]);
        float v2 = bf2f(gin[p.z & 0xFFFFFu]);
        float v3 = bf2f(gin[p.w & 0xFFFFFu]);
        atomicAdd(&acc[p.x >> 20], v0);
        atomicAdd(&acc[p.y >> 20], v1);
        atomicAdd(&acc[p.z >> 20], v2);
        atomicAdd(&acc[p.w >> 20], v3);
    }
    if (a1 + t < e) {
        unsigned p = binned[a1 + t];
        atomicAdd(&acc[p >> 20], bf2f(gin[p & 0xFFFFFu]));
    }
    __syncthreads();

    float w = wp[0];
    float bias = FINAL ? bp[0] : 0.f;
    int nodeBase = b << BINSHIFT;
    #pragma unroll
    for (int k = 0; k < BINSZ / RTH; ++k) {
        int node = nodeBase + t + k * RTH;
        if (node < n) {
            float h = fmaxf(acc[t + k * RTH] * w, 0.f);
            if (FINAL) fout[node] = 1.f / (1.f + __expf(-(h + bias)));
            else       hout[node] = f2bf(h);
        }
    }
}

// ========================= fallback (round-1) path =========================

__global__ void scatter_add4(const float* __restrict__ x,
                             const int* __restrict__ src,
                             const int* __restrict__ dst,
                             float* __restrict__ agg,
                             int nE4, int nE) {
    int tid = blockIdx.x * blockDim.x + threadIdx.x;
    int stride = gridDim.x * blockDim.x;
    for (int i = tid; i < nE4; i += stride) {
        int4 s = reinterpret_cast<const int4*>(src)[i];
        int4 d = reinterpret_cast<const int4*>(dst)[i];
        atomicAdd(&agg[d.x], x[s.x]);
        atomicAdd(&agg[d.y], x[s.y]);
        atomicAdd(&agg[d.z], x[s.z]);
        atomicAdd(&agg[d.w], x[s.w]);
    }
    int e = nE4 * 4 + tid;
    if (e < nE) atomicAdd(&agg[dst[e]], x[src[e]]);
}

__global__ void relu_scale4(float* __restrict__ a, const float* __restrict__ w, int n4) {
    float wv = w[0];
    int tid = blockIdx.x * blockDim.x + threadIdx.x;
    int stride = gridDim.x * blockDim.x;
    for (int i = tid; i < n4; i += stride) {
        float4 v = reinterpret_cast<float4*>(a)[i];
        v.x = fmaxf(v.x * wv, 0.0f);
        v.y = fmaxf(v.y * wv, 0.0f);
        v.z = fmaxf(v.z * wv, 0.0f);
        v.w = fmaxf(v.w * wv, 0.0f);
        reinterpret_cast<float4*>(a)[i] = v;
    }
}

__global__ void finish4(float* __restrict__ o, const float* __restrict__ w,
                        const float* __restrict__ bias, int n4) {
    float wv = w[0];
    float b = bias[0];
    int tid = blockIdx.x * blockDim.x + threadIdx.x;
    int stride = gridDim.x * blockDim.x;
    for (int i = tid; i < n4; i += stride) {
        float4 v = reinterpret_cast<float4*>(o)[i];
        float sx = fmaxf(v.x * wv, 0.0f) + b;
        float sy = fmaxf(v.y * wv, 0.0f) + b;
        float sz = fmaxf(v.z * wv, 0.0f) + b;
        float sw = fmaxf(v.w * wv, 0.0f) + b;
        v.x = 1.0f / (1.0f + __expf(-sx));
        v.y = 1.0f / (1.0f + __expf(-sy));
        v.z = 1.0f / (1.0f + __expf(-sz));
        v.w = 1.0f / (1.0f + __expf(-sw));
        reinterpret_cast<float4*>(o)[i] = v;
    }
}

// ========================= launcher =========================

extern "C" void kernel_launch(void* const* d_in, const int* in_sizes, int n_in,
                              void* d_out, int out_size, void* d_ws, size_t ws_size,
                              hipStream_t stream) {
    const float* x    = (const float*)d_in[0];
    const int*   ei   = (const int*)d_in[1];
    const float* w    = (const float*)d_in[2];
    const float* bias = (const float*)d_in[3];

    int n  = in_sizes[0];
    int nE = in_sizes[1] / 2;
    const int* src = ei;
    const int* dst = ei + nE;
    float* out = (float*)d_out;

    int NB = (n + BINSZ - 1) >> BINSHIFT;

    // capacity per bin: avg + max(avg/8, 4096), multiple of 4 (uint4 starts)
    int avg = (nE + (NB > 0 ? NB : 1) - 1) / (NB > 0 ? NB : 1);
    int slack = avg / 8; if (slack < 4096) slack = 4096;
    int CAP = (avg + slack + 3) & ~3;

    // ws layout: binned[NB*CAP] | cursors[512] | xb[n] bf16 | h1b[n] bf16
    size_t sz_binned = (((size_t)NB * (size_t)CAP) * 4 + 255) & ~(size_t)255;
    size_t sz_cur    = (MAXNB * 4 + 255) & ~(size_t)255;
    size_t sz_tab    = ((size_t)n * 2 + 255) & ~(size_t)255;
    size_t need      = sz_binned + sz_cur + 2 * sz_tab;

    bool can_fast = (n <= (1 << 20)) && (NB <= MAXNB) && (ws_size >= need);

    if (can_fast) {
        unsigned int*   binned  = (unsigned int*)d_ws;
        int*            cursors = (int*)((char*)d_ws + sz_binned);
        unsigned short* xb      = (unsigned short*)((char*)d_ws + sz_binned + sz_cur);
        unsigned short* h1b     = (unsigned short*)((char*)d_ws + sz_binned + sz_cur + sz_tab);

        dim3 blk256(256), blk512(512), blk1024(RTH);
        prep_kernel<<<1024, blk256, 0, stream>>>(x, xb, n, cursors, NB, CAP);

        int nChunks = (nE + SCHUNK - 1) / SCHUNK;
        scatter_staged<<<nChunks, blk512, 0, stream>>>(src, dst, nE, NB, CAP,
                                                       cursors, binned);

        reduce_bf<0><<<NB, blk1024, 0, stream>>>(binned, cursors, CAP, xb,
                                                 w + 0, bias, h1b, nullptr, n);
        reduce_bf<1><<<NB, blk1024, 0, stream>>>(binned, cursors, CAP, h1b,
                                                 w + 1, bias, nullptr, out, n);
    } else {
        float* agg1 = (float*)d_ws;
        hipMemsetAsync(agg1, 0, (size_t)n * sizeof(float), stream);
        hipMemsetAsync(out,  0, (size_t)n * sizeof(float), stream);
        int nE4 = nE / 4;
        dim3 blk(256);
        int eblocks = (nE4 + 255) / 256; if (eblocks > 4096) eblocks = 4096;
        int n4 = n / 4;
        int nblocks = (n4 + 255) / 256; if (nblocks > 2048) nblocks = 2048;
        scatter_add4<<<eblocks, blk, 0, stream>>>(x, src, dst, agg1, nE4, nE);
        relu_scale4<<<nblocks, blk, 0, stream>>>(agg1, w + 0, n4);
        scatter_add4<<<eblocks, blk, 0, stream>>>(agg1, src, dst, out, nE4, nE);
        finish4<<<nblocks, blk, 0, stream>>>(out, w + 1, bias, n4);
    }
}

// Round 13
// 248.344 us; speedup vs baseline: 1.1241x; 1.0345x over previous
//
#include <hip/hip_runtime.h>
#include <math.h>

// ---------------------------------------------------------------------------
// 2-layer graph conv (1-wide features), atomic-free via dst-binned counting
// sort (once, reused by both layers) + per-bin LDS accumulation.
//   layer: agg[v] = sum_{(u->v)} x[u];  x = relu(agg * w[i])
//   out   = sigmoid(x + bias)
// Packing: N <= 2^20, BINSZ=2048 -> meta = (dst_low11 << 20) | src20
// R13: R12 with the scatter at 1024 threads (2-pass, proven loops, scan
//      guarded to 512 lanes). 52-VGPR body fits the 64-VGPR tier ->
//      32 waves/CU (vs 16) at the same 2 blocks/CU LDS limit. Targets the
//      barrier/latency slack (VALU 20%, HBM 12% = mostly waiting).
// ---------------------------------------------------------------------------

#define BINSHIFT 11
#define BINSZ    2048
#define MAXNB    512
#define SCHUNK   16384
#define STH2     1024
#define RTH      1024

typedef unsigned u32x4 __attribute__((ext_vector_type(4)));

__device__ inline unsigned short f2bf(float f) {
    unsigned u = __float_as_uint(f);
    unsigned r = u + 0x7FFFu + ((u >> 16) & 1u);   // round-to-nearest-even
    return (unsigned short)(r >> 16);
}
__device__ inline float bf2f(unsigned short h) {
    return __uint_as_float(((unsigned)h) << 16);
}

// P: fused prep — convert fp32 x -> bf16 table, init cursors[b] = b*CAP
__global__ void prep_kernel(const float* __restrict__ x,
                            unsigned short* __restrict__ xb, int n,
                            int* __restrict__ cursors, int NB, int CAP) {
    int tid = blockIdx.x * blockDim.x + threadIdx.x;
    if (tid < NB) cursors[tid] = tid * CAP;
    int stride = gridDim.x * blockDim.x;
    for (int i = tid; i < n; i += stride) xb[i] = f2bf(x[i]);
}

// A: LDS-staged scatter, 2-pass (R8-proven loops), 1024 threads.
__global__ __launch_bounds__(STH2, 8)
void scatter_staged(const int* __restrict__ src, const int* __restrict__ dst,
                    int nE, int NB, int CAP, int* __restrict__ cursors,
                    unsigned int* __restrict__ binned) {
    __shared__ unsigned int stage[SCHUNK];   // 64 KB
    __shared__ int cnt[MAXNB];
    __shared__ int lstart[MAXNB];
    __shared__ int lscan[MAXNB];
    __shared__ int delta[MAXNB];

    int t = threadIdx.x;
    int cb = blockIdx.x * SCHUNK;
    int nHere = nE - cb;
    if (nHere > SCHUNK) nHere = SCHUNK;

    if (t < MAXNB) cnt[t] = 0;
    __syncthreads();

    // ---- pass 1: count this chunk's bins ----
    if (nHere == SCHUNK) {
        const int4* d4 = reinterpret_cast<const int4*>(dst + cb);
        #pragma unroll
        for (int k = 0; k < SCHUNK / 4 / STH2; ++k) {   // 4 iters
            int4 d = d4[k * STH2 + t];
            atomicAdd(&cnt[d.x >> BINSHIFT], 1);
            atomicAdd(&cnt[d.y >> BINSHIFT], 1);
            atomicAdd(&cnt[d.z >> BINSHIFT], 1);
            atomicAdd(&cnt[d.w >> BINSHIFT], 1);
        }
    } else {
        for (int j = t; j < nHere; j += STH2)
            atomicAdd(&cnt[dst[cb + j] >> BINSHIFT], 1);
    }
    __syncthreads();

    // ---- scan (Hillis-Steele over 512; barriers uniform across 1024) ----
    int c = 0;
    if (t < MAXNB) { c = cnt[t]; lscan[t] = c; }
    __syncthreads();
    for (int off = 1; off < MAXNB; off <<= 1) {
        int v = 0;
        if (t < MAXNB && t >= off) v = lscan[t - off];
        __syncthreads();
        if (t < MAXNB) lscan[t] += v;
        __syncthreads();
    }
    if (t < MAXNB) {
        lstart[t] = lscan[t] - c;
        int gb = 0;
        if (t < NB && c) gb = atomicAdd(&cursors[t], c);
        delta[t] = gb - (lscan[t] - c);
        cnt[t] = 0;
    }
    __syncthreads();

    // ---- pass 2: rank + stage (bin-ordered); dst/src re-read is L2-hot ----
    if (nHere == SCHUNK) {
        const int4* d4 = reinterpret_cast<const int4*>(dst + cb);
        const int4* s4 = reinterpret_cast<const int4*>(src + cb);
        #pragma unroll
        for (int k = 0; k < SCHUNK / 4 / STH2; ++k) {
            int4 d = d4[k * STH2 + t];
            int4 s = s4[k * STH2 + t];
            int b, r;
            b = d.x >> BINSHIFT; r = atomicAdd(&cnt[b], 1);
            stage[lstart[b] + r] = ((unsigned)(d.x & (BINSZ - 1)) << 20) | (unsigned)s.x;
            b = d.y >> BINSHIFT; r = atomicAdd(&cnt[b], 1);
            stage[lstart[b] + r] = ((unsigned)(d.y & (BINSZ - 1)) << 20) | (unsigned)s.y;
            b = d.z >> BINSHIFT; r = atomicAdd(&cnt[b], 1);
            stage[lstart[b] + r] = ((unsigned)(d.z & (BINSZ - 1)) << 20) | (unsigned)s.z;
            b = d.w >> BINSHIFT; r = atomicAdd(&cnt[b], 1);
            stage[lstart[b] + r] = ((unsigned)(d.w & (BINSZ - 1)) << 20) | (unsigned)s.w;
        }
    } else {
        for (int j = t; j < nHere; j += STH2) {
            int dv = dst[cb + j];
            int sv = src[cb + j];
            int b = dv >> BINSHIFT;
            int r = atomicAdd(&cnt[b], 1);
            stage[lstart[b] + r] = ((unsigned)(dv & (BINSZ - 1)) << 20) | (unsigned)sv;
        }
    }
    __syncthreads();

    // ---- copy-out: one wave per bin (16 waves), coalesced segment copy ----
    int wave = t >> 6, lane = t & 63;
    for (int b = wave; b < NB; b += STH2 / 64) {
        int s0 = lstart[b];
        int s1 = lscan[b];
        int dlt = delta[b];
        int gmax = (b + 1) * CAP;
        for (int j = s0 + lane; j < s1; j += 64) {
            int gi = dlt + j;
            if (gi < gmax) binned[gi] = stage[j];   // capacity clamp
        }
    }
}

// B: per-bin reduce, bf16 gather table (R12 body).
template <int FINAL>
__global__ __launch_bounds__(RTH, 8)
void reduce_bf(const unsigned int* __restrict__ binned,
               const int* __restrict__ cursors, int CAP,
               const unsigned short* __restrict__ gin,
               const float* __restrict__ wp,
               const float* __restrict__ bp,
               unsigned short* __restrict__ hout,
               float* __restrict__ fout, int n) {
    __shared__ float acc[BINSZ];
    int b = blockIdx.x;
    int t = threadIdx.x;
    acc[t] = 0.f;
    acc[t + RTH] = 0.f;
    __syncthreads();

    int s = b * CAP;            // CAP % 4 == 0 -> 16B-aligned start
    int e = cursors[b];
    int a1 = e & ~3;

    const u32x4* b4 = reinterpret_cast<const u32x4*>(binned);
    int q1 = a1 >> 2;
    int q = (s >> 2) + t;
    for (; q + RTH < q1; q += 2 * RTH) {
        u32x4 pA = b4[q];
        u32x4 pB = b4[q + RTH];
        float v0 = bf2f(gin[pA.x & 0xFFFFFu]);
        float v1 = bf2f(gin[pA.y & 0xFFFFFu]);
        float v2 = bf2f(gin[pA.z & 0xFFFFFu]);
        float v3 = bf2f(gin[pA.w & 0xFFFFFu]);
        float v4 = bf2f(gin[pB.x & 0xFFFFFu]);
        float v5 = bf2f(gin[pB.y & 0xFFFFFu]);
        float v6 = bf2f(gin[pB.z & 0xFFFFFu]);
        float v7 = bf2f(gin[pB.w & 0xFFFFFu]);
        atomicAdd(&acc[pA.x >> 20], v0);
        atomicAdd(&acc[pA.y >> 20], v1);
        atomicAdd(&acc[pA.z >> 20], v2);
        atomicAdd(&acc[pA.w >> 20], v3);
        atomicAdd(&acc[pB.x >> 20], v4);
        atomicAdd(&acc[pB.y >> 20], v5);
        atomicAdd(&acc[pB.z >> 20], v6);
        atomicAdd(&acc[pB.w >> 20], v7);
    }
    for (; q < q1; q += RTH) {
        u32x4 p = b4[q];
        float v0 = bf2f(gin[p.x & 0xFFFFFu]);
        float v1 = bf2f(gin[p.y & 0xFFFFFu]);
        float v2 = bf2f(gin[p.z & 0xFFFFFu]);
        float v3 = bf2f(gin[p.w & 0xFFFFFu]);
        atomicAdd(&acc[p.x >> 20], v0);
        atomicAdd(&acc[p.y >> 20], v1);
        atomicAdd(&acc[p.z >> 20], v2);
        atomicAdd(&acc[p.w >> 20], v3);
    }
    if (a1 + t < e) {
        unsigned p = binned[a1 + t];
        atomicAdd(&acc[p >> 20], bf2f(gin[p & 0xFFFFFu]));
    }
    __syncthreads();

    float w = wp[0];
    float bias = FINAL ? bp[0] : 0.f;
    int nodeBase = b << BINSHIFT;
    #pragma unroll
    for (int k = 0; k < BINSZ / RTH; ++k) {
        int node = nodeBase + t + k * RTH;
        if (node < n) {
            float h = fmaxf(acc[t + k * RTH] * w, 0.f);
            if (FINAL) fout[node] = 1.f / (1.f + __expf(-(h + bias)));
            else       hout[node] = f2bf(h);
        }
    }
}

// ========================= fallback (round-1) path =========================

__global__ void scatter_add4(const float* __restrict__ x,
                             const int* __restrict__ src,
                             const int* __restrict__ dst,
                             float* __restrict__ agg,
                             int nE4, int nE) {
    int tid = blockIdx.x * blockDim.x + threadIdx.x;
    int stride = gridDim.x * blockDim.x;
    for (int i = tid; i < nE4; i += stride) {
        int4 s = reinterpret_cast<const int4*>(src)[i];
        int4 d = reinterpret_cast<const int4*>(dst)[i];
        atomicAdd(&agg[d.x], x[s.x]);
        atomicAdd(&agg[d.y], x[s.y]);
        atomicAdd(&agg[d.z], x[s.z]);
        atomicAdd(&agg[d.w], x[s.w]);
    }
    int e = nE4 * 4 + tid;
    if (e < nE) atomicAdd(&agg[dst[e]], x[src[e]]);
}

__global__ void relu_scale4(float* __restrict__ a, const float* __restrict__ w, int n4) {
    float wv = w[0];
    int tid = blockIdx.x * blockDim.x + threadIdx.x;
    int stride = gridDim.x * blockDim.x;
    for (int i = tid; i < n4; i += stride) {
        float4 v = reinterpret_cast<float4*>(a)[i];
        v.x = fmaxf(v.x * wv, 0.0f);
        v.y = fmaxf(v.y * wv, 0.0f);
        v.z = fmaxf(v.z * wv, 0.0f);
        v.w = fmaxf(v.w * wv, 0.0f);
        reinterpret_cast<float4*>(a)[i] = v;
    }
}

__global__ void finish4(float* __restrict__ o, const float* __restrict__ w,
                        const float* __restrict__ bias, int n4) {
    float wv = w[0];
    float b = bias[0];
    int tid = blockIdx.x * blockDim.x + threadIdx.x;
    int stride = gridDim.x * blockDim.x;
    for (int i = tid; i < n4; i += stride) {
        float4 v = reinterpret_cast<float4*>(o)[i];
        float sx = fmaxf(v.x * wv, 0.0f) + b;
        float sy = fmaxf(v.y * wv, 0.0f) + b;
        float sz = fmaxf(v.z * wv, 0.0f) + b;
        float sw = fmaxf(v.w * wv, 0.0f) + b;
        v.x = 1.0f / (1.0f + __expf(-sx));
        v.y = 1.0f / (1.0f + __expf(-sy));
        v.z = 1.0f / (1.0f + __expf(-sz));
        v.w = 1.0f / (1.0f + __expf(-sw));
        reinterpret_cast<float4*>(o)[i] = v;
    }
}

// ========================= launcher =========================

extern "C" void kernel_launch(void* const* d_in, const int* in_sizes, int n_in,
                              void* d_out, int out_size, void* d_ws, size_t ws_size,
                              hipStream_t stream) {
    const float* x    = (const float*)d_in[0];
    const int*   ei   = (const int*)d_in[1];
    const float* w    = (const float*)d_in[2];
    const float* bias = (const float*)d_in[3];

    int n  = in_sizes[0];
    int nE = in_sizes[1] / 2;
    const int* src = ei;
    const int* dst = ei + nE;
    float* out = (float*)d_out;

    int NB = (n + BINSZ - 1) >> BINSHIFT;

    // capacity per bin: avg + max(avg/8, 4096), multiple of 4 (uint4 starts)
    int avg = (nE + (NB > 0 ? NB : 1) - 1) / (NB > 0 ? NB : 1);
    int slack = avg / 8; if (slack < 4096) slack = 4096;
    int CAP = (avg + slack + 3) & ~3;

    // ws layout: binned[NB*CAP] | cursors[512] | xb[n] bf16 | h1b[n] bf16
    size_t sz_binned = (((size_t)NB * (size_t)CAP) * 4 + 255) & ~(size_t)255;
    size_t sz_cur    = (MAXNB * 4 + 255) & ~(size_t)255;
    size_t sz_tab    = ((size_t)n * 2 + 255) & ~(size_t)255;
    size_t need      = sz_binned + sz_cur + 2 * sz_tab;

    bool can_fast = (n <= (1 << 20)) && (NB <= MAXNB) && (ws_size >= need);

    if (can_fast) {
        unsigned int*   binned  = (unsigned int*)d_ws;
        int*            cursors = (int*)((char*)d_ws + sz_binned);
        unsigned short* xb      = (unsigned short*)((char*)d_ws + sz_binned + sz_cur);
        unsigned short* h1b     = (unsigned short*)((char*)d_ws + sz_binned + sz_cur + sz_tab);

        dim3 blk256(256), blk1024(RTH);
        prep_kernel<<<1024, blk256, 0, stream>>>(x, xb, n, cursors, NB, CAP);

        int nChunks = (nE + SCHUNK - 1) / SCHUNK;
        scatter_staged<<<nChunks, dim3(STH2), 0, stream>>>(src, dst, nE, NB, CAP,
                                                           cursors, binned);

        reduce_bf<0><<<NB, blk1024, 0, stream>>>(binned, cursors, CAP, xb,
                                                 w + 0, bias, h1b, nullptr, n);
        reduce_bf<1><<<NB, blk1024, 0, stream>>>(binned, cursors, CAP, h1b,
                                                 w + 1, bias, nullptr, out, n);
    } else {
        float* agg1 = (float*)d_ws;
        hipMemsetAsync(agg1, 0, (size_t)n * sizeof(float), stream);
        hipMemsetAsync(out,  0, (size_t)n * sizeof(float), stream);
        int nE4 = nE / 4;
        dim3 blk(256);
        int eblocks = (nE4 + 255) / 256; if (eblocks > 4096) eblocks = 4096;
        int n4 = n / 4;
        int nblocks = (n4 + 255) / 256; if (nblocks > 2048) nblocks = 2048;
        scatter_add4<<<eblocks, blk, 0, stream>>>(x, src, dst, agg1, nE4, nE);
        relu_scale4<<<nblocks, blk, 0, stream>>>(agg1, w + 0, n4);
        scatter_add4<<<eblocks, blk, 0, stream>>>(agg1, src, dst, out, nE4, nE);
        finish4<<<nblocks, blk, 0, stream>>>(out, w + 1, bias, n4);
    }
}